// Round 4
// baseline (470.837 us; speedup 1.0000x reference)
//
#include <hip/hip_runtime.h>

// ---------------------------------------------------------------------------
// G_CAM_Module: out = gamma * (GA @ x) + x, where GA comes from a chain of
// softmaxed 64x64 Gram matrices of x and g.
//
//   A) gram_kernel  : per-chunk partial Grams of x and g via MFMA f16
//   B) reduce_kernel: sum 64 chunk-partials -> ex[b], eg[b]
//   C) chain_kernel : softmax chain -> M = gamma*GA + I          (tiny, fp32)
//   D) apply_kernel : out[b] = M[b] @ x_b
//      xv[64] pinned in VGPRs (asm), M via uniform global reads -> s_load.
// ---------------------------------------------------------------------------

typedef _Float16 h8 __attribute__((ext_vector_type(8)));
typedef float    f4 __attribute__((ext_vector_type(4)));
typedef __fp16   p2 __attribute__((ext_vector_type(2)));   // cvt_pkrtz result

#define NB 16
#define NC 64
#define NPIX 65536
#define GRAM_CHUNK 1024                 // pixels per gram block
#define PASS_PX 128                     // pixels per LDS pass
#define NPASS (GRAM_CHUNK / PASS_PX)    // 8
#define NCHUNK (NPIX / GRAM_CHUNK)      // 64
#define ROW_H 136                       // halves per LDS row (128 data + 8 pad)
#define LDS_H (64 * ROW_H + 64)         // halves per matrix (incl. row-group pads)

__device__ __forceinline__ int rowbase_h(int c) {
    return c * ROW_H + (c >> 3) * 8;
}

__device__ __forceinline__ unsigned int pk(float a, float b) {
    p2 v = __builtin_amdgcn_cvt_pkrtz(a, b);
    return __builtin_bit_cast(unsigned int, v);
}

// ---- Kernel A: partial Gram matrices via MFMA -----------------------------
// grid (64, 16), 512 threads = 8 waves. Waves 0-3: x-gram row-blocks 0-3;
// waves 4-7: g-gram. Each wave computes a 16x64 slice of the 64x64 Gram.
__global__ __launch_bounds__(512, 4) void gram_kernel(
    const float* __restrict__ x, const float* __restrict__ g,
    float* __restrict__ part)
{
    __shared__ __align__(16) _Float16 lds[2 * LDS_H];
    _Float16* xs = lds;
    _Float16* gs = lds + LDS_H;

    const int tid = threadIdx.x;
    const int b = blockIdx.y;
    const size_t cbase = (size_t)b * NC * NPIX + (size_t)blockIdx.x * GRAM_CHUNK;

    const int w     = tid >> 6;
    const int lane  = tid & 63;
    const int mtx   = w >> 2;         // 0: x, 1: g
    const int rb    = w & 3;          // C row-block (16 rows)
    const int l15   = lane & 15;
    const int khalf = lane >> 4;      // 0..3 -> which 8-elem k-group
    const _Float16* mybuf = mtx ? gs : xs;

    const int abase_h = rowbase_h(rb * 16 + l15);

    f4 acc[4];
    #pragma unroll
    for (int cb = 0; cb < 4; ++cb) acc[cb] = (f4){0.f, 0.f, 0.f, 0.f};

    for (int pass = 0; pass < NPASS; ++pass) {
        const size_t pbase = cbase + (size_t)pass * PASS_PX;
        #pragma unroll
        for (int it = 0; it < 4; ++it) {
            int e = it * 512 + tid;       // 0..2047
            int c = e >> 5;               // channel
            int q = e & 31;               // float4 index within 128 px
            f4 vx = *(const f4*)(x + pbase + (size_t)c * NPIX + q * 4);
            f4 vg = *(const f4*)(g + pbase + (size_t)c * NPIX + q * 4);
            unsigned long long hx =
                (unsigned long long)pk(vx.x, vx.y) | ((unsigned long long)pk(vx.z, vx.w) << 32);
            unsigned long long hg =
                (unsigned long long)pk(vg.x, vg.y) | ((unsigned long long)pk(vg.z, vg.w) << 32);
            int off = rowbase_h(c) + q * 4;
            *reinterpret_cast<unsigned long long*>(&xs[off]) = hx;
            *reinterpret_cast<unsigned long long*>(&gs[off]) = hg;
        }
        __syncthreads();

        #pragma unroll
        for (int ks = 0; ks < 4; ++ks) {
            int koff = ks * 32 + khalf * 8;   // halves into the row
            h8 a = *reinterpret_cast<const h8*>(&mybuf[abase_h + koff]);
            #pragma unroll
            for (int cb = 0; cb < 4; ++cb) {
                h8 bf = *reinterpret_cast<const h8*>(&mybuf[rowbase_h(cb * 16 + l15) + koff]);
                acc[cb] = __builtin_amdgcn_mfma_f32_16x16x32_f16(a, bf, acc[cb], 0, 0, 0);
            }
        }
        __syncthreads();
    }

    float* po = part + (((size_t)blockIdx.x * NB + b) * 2 + mtx) * 4096;
    #pragma unroll
    for (int cb = 0; cb < 4; ++cb)
        #pragma unroll
        for (int r = 0; r < 4; ++r)
            po[(rb * 16 + khalf * 4 + r) * 64 + cb * 16 + l15] = acc[cb][r];
}

// ---- Kernel B: reduce 64 chunk-partials -> ex, eg -------------------------
__global__ __launch_bounds__(256) void reduce_kernel(
    const float* __restrict__ part, float* __restrict__ ex, float* __restrict__ eg)
{
    const int idx = blockIdx.x * 256 + threadIdx.x;
    const int bm = idx >> 12;          // b*2 + m
    const int cd = idx & 4095;
    float s = 0.f;
    #pragma unroll 8
    for (int ch = 0; ch < NCHUNK; ++ch)
        s += part[(size_t)ch * (NB * 2 * 4096) + (size_t)bm * 4096 + cd];
    float* dst = (bm & 1) ? eg : ex;
    dst[(bm >> 1) * 4096 + cd] = s;
}

// ---- Kernel C: softmax chain -> M = gamma*GA + I -------------------------
__global__ __launch_bounds__(256) void chain_kernel(
    const float* __restrict__ ex, const float* __restrict__ eg,
    const float* __restrict__ gammap, float* __restrict__ M)
{
    __shared__ float A1[64][68];
    __shared__ float A2[64][68];
    __shared__ float red[64][4];

    const int b = blockIdx.x;
    const int tid = threadIdx.x;

    if (tid < 64) {
        const int c = tid;
        float r[64];
        #pragma unroll
        for (int d = 0; d < 64; ++d) r[d] = ex[b * 4096 + c * 64 + d];
        float mx = r[0];
        #pragma unroll
        for (int d = 1; d < 64; ++d) mx = fmaxf(mx, r[d]);
        float s = 0.f;
        #pragma unroll
        for (int d = 0; d < 64; ++d) { r[d] = expf(r[d] - mx); s += r[d]; }
        float inv = 1.f / s;
        #pragma unroll
        for (int d = 0; d < 64; ++d) A1[c][d] = r[d] * inv;

        #pragma unroll
        for (int d = 0; d < 64; ++d) r[d] = eg[b * 4096 + c * 64 + d];
        mx = r[0];
        #pragma unroll
        for (int d = 1; d < 64; ++d) mx = fmaxf(mx, r[d]);
        s = 0.f;
        #pragma unroll
        for (int d = 0; d < 64; ++d) { r[d] = expf(r[d] - mx); s += r[d]; }
        inv = 1.f / s;
        #pragma unroll
        for (int d = 0; d < 64; ++d) A2[c][d] = r[d] * inv;
    }
    __syncthreads();

    const int c = tid >> 2, sq = tid & 3;
    float ge[16];
    #pragma unroll
    for (int k = 0; k < 16; ++k) ge[k] = 0.f;
    for (int d = 0; d < 64; ++d) {
        float a = A1[c][d];
        const float* row = &A2[d][sq * 16];
        #pragma unroll
        for (int k = 0; k < 16; ++k) ge[k] = fmaf(a, row[k], ge[k]);
    }

    float mx = ge[0];
    #pragma unroll
    for (int k = 1; k < 16; ++k) mx = fmaxf(mx, ge[k]);
    red[c][sq] = mx;
    __syncthreads();
    float gm = fmaxf(fmaxf(red[c][0], red[c][1]), fmaxf(red[c][2], red[c][3]));
    __syncthreads();

    float gen[16];
    #pragma unroll
    for (int k = 0; k < 16; ++k) gen[k] = gm - ge[k];
    float mx2 = gen[0];
    #pragma unroll
    for (int k = 1; k < 16; ++k) mx2 = fmaxf(mx2, gen[k]);
    red[c][sq] = mx2;
    __syncthreads();
    float m2 = fmaxf(fmaxf(red[c][0], red[c][1]), fmaxf(red[c][2], red[c][3]));
    __syncthreads();

    float p[16];
    float s = 0.f;
    #pragma unroll
    for (int k = 0; k < 16; ++k) { p[k] = expf(gen[k] - m2); s += p[k]; }
    red[c][sq] = s;
    __syncthreads();
    float S = red[c][0] + red[c][1] + red[c][2] + red[c][3];

    float gam = gammap[0];
    float invS = 1.f / S;
    #pragma unroll
    for (int k = 0; k < 16; ++k) {
        int e = sq * 16 + k;
        M[b * 4096 + c * 64 + e] = gam * p[k] * invS + (e == c ? 1.f : 0.f);
    }
}

// ---- Kernel D: out[b] = M[b] @ x[b] ---------------------------------------
// grid (256, 16), 256 threads; thread owns one pixel column (64 in, 64 out).
// xv[64] pinned into VGPRs via asm; M read with block-uniform indices so the
// compiler scalarizes to s_load + SGPR-operand FMAs (no LDS, no VGPR cost).
__global__ __launch_bounds__(256, 2) void apply_kernel(
    const float* __restrict__ x, const float* __restrict__ M,
    float* __restrict__ out)
{
    const int b = blockIdx.y;
    const int tid = threadIdx.x;
    const int n = blockIdx.x * 256 + tid;
    const float* xb = x + (size_t)b * NC * NPIX + n;
    float* ob = out + (size_t)b * NC * NPIX + n;

    float xv[64];
    #pragma unroll
    for (int d = 0; d < 64; ++d) xv[d] = xb[(size_t)d * NPIX];
    // Pin each element into a VGPR: forbids the compiler from rematerializing
    // the loads inside the c-loop (R3 showed VGPR_Count=44 -> it had done so).
    #pragma unroll
    for (int d = 0; d < 64; ++d) asm volatile("" : "+v"(xv[d]));

    const float* __restrict__ Mb = M + b * 4096;   // block-uniform
    #pragma unroll 8
    for (int c = 0; c < 64; ++c) {
        float a0 = 0.f, a1 = 0.f, a2 = 0.f, a3 = 0.f;
        #pragma unroll
        for (int k = 0; k < 16; ++k) {
            a0 = fmaf(Mb[c * 64 + 4 * k + 0], xv[4 * k + 0], a0);
            a1 = fmaf(Mb[c * 64 + 4 * k + 1], xv[4 * k + 1], a1);
            a2 = fmaf(Mb[c * 64 + 4 * k + 2], xv[4 * k + 2], a2);
            a3 = fmaf(Mb[c * 64 + 4 * k + 3], xv[4 * k + 3], a3);
        }
        ob[(size_t)c * NPIX] = (a0 + a1) + (a2 + a3);
    }
}

extern "C" void kernel_launch(void* const* d_in, const int* in_sizes, int n_in,
                              void* d_out, int out_size, void* d_ws, size_t ws_size,
                              hipStream_t stream) {
    const float* x     = (const float*)d_in[0];
    const float* g     = (const float*)d_in[1];
    const float* gamma = (const float*)d_in[2];
    float* out = (float*)d_out;
    float* ws  = (float*)d_ws;

    float* ex = ws;                  // 16*4096 floats
    float* eg = ws + NB * 4096;      // 16*4096 floats
    float* M  = ws + 2 * NB * 4096;  // 16*4096 floats

    // d_out doubles as scratch for the 33.5 MB gram partials; apply_kernel
    // fully overwrites d_out afterwards (stream-ordered), so this is safe.
    float* part = out;

    gram_kernel<<<dim3(NCHUNK, NB), 512, 0, stream>>>(x, g, part);
    reduce_kernel<<<512, 256, 0, stream>>>(part, ex, eg);
    chain_kernel<<<NB, 256, 0, stream>>>(ex, eg, gamma, M);
    apply_kernel<<<dim3(NPIX / 256, NB), 256, 0, stream>>>(x, M, out);
}

// Round 5
// 286.266 us; speedup vs baseline: 1.6448x; 1.6448x over previous
//
#include <hip/hip_runtime.h>

// ---------------------------------------------------------------------------
// G_CAM_Module: out = gamma * (GA @ x) + x, where GA comes from a chain of
// softmaxed 64x64 Gram matrices of x and g.
//
//   A) gram_kernel  : per-chunk partial Grams of x and g via MFMA f16
//   B) reduce_kernel: sum 64 chunk-partials -> ex[b], eg[b]
//   C) chain_kernel : softmax chain -> M = gamma*GA   (NO identity; tiny fp32)
//   D) apply_kernel : out[b] = M[b] @ x_b + x_b via MFMA f16,
//                     fp32 residual added in the epilogue (x re-read = L2 hit)
//
// MFMA fragment mapping (A row = lane&15, B col = lane&15, k-group =
// (lane>>4)*8, C/D col = lane&15 / row = (lane>>4)*4+reg) is end-to-end
// verified by R2/R3's gram kernel passing vs the reference.
// ---------------------------------------------------------------------------

typedef _Float16 h8 __attribute__((ext_vector_type(8)));
typedef float    f4 __attribute__((ext_vector_type(4)));
typedef __fp16   p2 __attribute__((ext_vector_type(2)));   // cvt_pkrtz result

#define NB 16
#define NC 64
#define NPIX 65536
#define GRAM_CHUNK 1024                 // pixels per gram block
#define PASS_PX 128                     // pixels per LDS pass
#define NPASS (GRAM_CHUNK / PASS_PX)    // 8
#define NCHUNK (NPIX / GRAM_CHUNK)      // 64
#define ROW_H 136                       // gram LDS row stride (halves)
#define LDS_H (64 * ROW_H + 64)

#define AP_NPX 256                      // apply: pixels per block
#define XT_ROW 72                       // apply: xT row stride in halves (144B)

__device__ __forceinline__ int rowbase_h(int c) {
    return c * ROW_H + (c >> 3) * 8;
}

__device__ __forceinline__ unsigned int pk(float a, float b) {
    p2 v = __builtin_amdgcn_cvt_pkrtz(a, b);
    return __builtin_bit_cast(unsigned int, v);
}

// ---- Kernel A: partial Gram matrices via MFMA -----------------------------
// grid (64, 16), 512 threads = 8 waves. Waves 0-3: x-gram row-blocks 0-3;
// waves 4-7: g-gram. Each wave computes a 16x64 slice of the 64x64 Gram.
__global__ __launch_bounds__(512, 4) void gram_kernel(
    const float* __restrict__ x, const float* __restrict__ g,
    float* __restrict__ part)
{
    __shared__ __align__(16) _Float16 lds[2 * LDS_H];
    _Float16* xs = lds;
    _Float16* gs = lds + LDS_H;

    const int tid = threadIdx.x;
    const int b = blockIdx.y;
    const size_t cbase = (size_t)b * NC * NPIX + (size_t)blockIdx.x * GRAM_CHUNK;

    const int w     = tid >> 6;
    const int lane  = tid & 63;
    const int mtx   = w >> 2;         // 0: x, 1: g
    const int rb    = w & 3;          // C row-block (16 rows)
    const int l15   = lane & 15;
    const int khalf = lane >> 4;      // 0..3 -> which 8-elem k-group
    const _Float16* mybuf = mtx ? gs : xs;

    const int abase_h = rowbase_h(rb * 16 + l15);

    f4 acc[4];
    #pragma unroll
    for (int cb = 0; cb < 4; ++cb) acc[cb] = (f4){0.f, 0.f, 0.f, 0.f};

    for (int pass = 0; pass < NPASS; ++pass) {
        const size_t pbase = cbase + (size_t)pass * PASS_PX;
        #pragma unroll
        for (int it = 0; it < 4; ++it) {
            int e = it * 512 + tid;       // 0..2047
            int c = e >> 5;               // channel
            int q = e & 31;               // float4 index within 128 px
            f4 vx = *(const f4*)(x + pbase + (size_t)c * NPIX + q * 4);
            f4 vg = *(const f4*)(g + pbase + (size_t)c * NPIX + q * 4);
            unsigned long long hx =
                (unsigned long long)pk(vx.x, vx.y) | ((unsigned long long)pk(vx.z, vx.w) << 32);
            unsigned long long hg =
                (unsigned long long)pk(vg.x, vg.y) | ((unsigned long long)pk(vg.z, vg.w) << 32);
            int off = rowbase_h(c) + q * 4;
            *reinterpret_cast<unsigned long long*>(&xs[off]) = hx;
            *reinterpret_cast<unsigned long long*>(&gs[off]) = hg;
        }
        __syncthreads();

        #pragma unroll
        for (int ks = 0; ks < 4; ++ks) {
            int koff = ks * 32 + khalf * 8;
            h8 a = *reinterpret_cast<const h8*>(&mybuf[abase_h + koff]);
            #pragma unroll
            for (int cb = 0; cb < 4; ++cb) {
                h8 bf = *reinterpret_cast<const h8*>(&mybuf[rowbase_h(cb * 16 + l15) + koff]);
                acc[cb] = __builtin_amdgcn_mfma_f32_16x16x32_f16(a, bf, acc[cb], 0, 0, 0);
            }
        }
        __syncthreads();
    }

    float* po = part + (((size_t)blockIdx.x * NB + b) * 2 + mtx) * 4096;
    #pragma unroll
    for (int cb = 0; cb < 4; ++cb)
        #pragma unroll
        for (int r = 0; r < 4; ++r)
            po[(rb * 16 + khalf * 4 + r) * 64 + cb * 16 + l15] = acc[cb][r];
}

// ---- Kernel B: reduce 64 chunk-partials -> ex, eg -------------------------
__global__ __launch_bounds__(256) void reduce_kernel(
    const float* __restrict__ part, float* __restrict__ ex, float* __restrict__ eg)
{
    const int idx = blockIdx.x * 256 + threadIdx.x;
    const int bm = idx >> 12;          // b*2 + m
    const int cd = idx & 4095;
    float s = 0.f;
    #pragma unroll 8
    for (int ch = 0; ch < NCHUNK; ++ch)
        s += part[(size_t)ch * (NB * 2 * 4096) + (size_t)bm * 4096 + cd];
    float* dst = (bm & 1) ? eg : ex;
    dst[(bm >> 1) * 4096 + cd] = s;
}

// ---- Kernel C: softmax chain -> M = gamma*GA (no identity) ----------------
__global__ __launch_bounds__(256) void chain_kernel(
    const float* __restrict__ ex, const float* __restrict__ eg,
    const float* __restrict__ gammap, float* __restrict__ M)
{
    __shared__ float A1[64][68];
    __shared__ float A2[64][68];
    __shared__ float red[64][4];

    const int b = blockIdx.x;
    const int tid = threadIdx.x;

    if (tid < 64) {
        const int c = tid;
        float r[64];
        #pragma unroll
        for (int d = 0; d < 64; ++d) r[d] = ex[b * 4096 + c * 64 + d];
        float mx = r[0];
        #pragma unroll
        for (int d = 1; d < 64; ++d) mx = fmaxf(mx, r[d]);
        float s = 0.f;
        #pragma unroll
        for (int d = 0; d < 64; ++d) { r[d] = expf(r[d] - mx); s += r[d]; }
        float inv = 1.f / s;
        #pragma unroll
        for (int d = 0; d < 64; ++d) A1[c][d] = r[d] * inv;

        #pragma unroll
        for (int d = 0; d < 64; ++d) r[d] = eg[b * 4096 + c * 64 + d];
        mx = r[0];
        #pragma unroll
        for (int d = 1; d < 64; ++d) mx = fmaxf(mx, r[d]);
        s = 0.f;
        #pragma unroll
        for (int d = 0; d < 64; ++d) { r[d] = expf(r[d] - mx); s += r[d]; }
        inv = 1.f / s;
        #pragma unroll
        for (int d = 0; d < 64; ++d) A2[c][d] = r[d] * inv;
    }
    __syncthreads();

    const int c = tid >> 2, sq = tid & 3;
    float ge[16];
    #pragma unroll
    for (int k = 0; k < 16; ++k) ge[k] = 0.f;
    for (int d = 0; d < 64; ++d) {
        float a = A1[c][d];
        const float* row = &A2[d][sq * 16];
        #pragma unroll
        for (int k = 0; k < 16; ++k) ge[k] = fmaf(a, row[k], ge[k]);
    }

    float mx = ge[0];
    #pragma unroll
    for (int k = 1; k < 16; ++k) mx = fmaxf(mx, ge[k]);
    red[c][sq] = mx;
    __syncthreads();
    float gm = fmaxf(fmaxf(red[c][0], red[c][1]), fmaxf(red[c][2], red[c][3]));
    __syncthreads();

    float gen[16];
    #pragma unroll
    for (int k = 0; k < 16; ++k) gen[k] = gm - ge[k];
    float mx2 = gen[0];
    #pragma unroll
    for (int k = 1; k < 16; ++k) mx2 = fmaxf(mx2, gen[k]);
    red[c][sq] = mx2;
    __syncthreads();
    float m2 = fmaxf(fmaxf(red[c][0], red[c][1]), fmaxf(red[c][2], red[c][3]));
    __syncthreads();

    float p[16];
    float s = 0.f;
    #pragma unroll
    for (int k = 0; k < 16; ++k) { p[k] = expf(gen[k] - m2); s += p[k]; }
    red[c][sq] = s;
    __syncthreads();
    float S = red[c][0] + red[c][1] + red[c][2] + red[c][3];

    float gam = gammap[0];
    float invS = 1.f / S;
    #pragma unroll
    for (int k = 0; k < 16; ++k) {
        int e = sq * 16 + k;
        M[b * 4096 + c * 64 + e] = gam * p[k] * invS;   // NO +I: residual in apply
    }
}

// ---- Kernel D: out[b] = M[b] @ x[b] + x[b] via MFMA ------------------------
// grid (256, 16), 256 threads = 4 waves. Block stages xT (256px x 64d, f16,
// transposed) + Ml (64x64 f16); wave w computes the 64c x 64n tile at
// n = w*64; epilogue adds fp32 x (L2-hot re-read) and stores.
__global__ __launch_bounds__(256) void apply_kernel(
    const float* __restrict__ x, const float* __restrict__ M,
    float* __restrict__ out)
{
    __shared__ __align__(16) _Float16 xT[AP_NPX * XT_ROW];   // 36864 B
    __shared__ __align__(16) _Float16 Ml[64 * XT_ROW];       //  9216 B

    const int tid = threadIdx.x;
    const int b = blockIdx.y;
    const int n0 = blockIdx.x * AP_NPX;
    const float* xb = x + (size_t)b * NC * NPIX + n0;

    // ---- stage xT: 32 d-pairs x 64 f4-cols = 2048 items / 256 threads ----
    #pragma unroll
    for (int it = 0; it < 8; ++it) {
        int e = it * 256 + tid;
        int q  = e & 63;          // f4 col (4 pixels)
        int dp = e >> 6;          // d-pair 0..31
        f4 va = *(const f4*)(xb + (size_t)(2 * dp)     * NPIX + q * 4);
        f4 vb = *(const f4*)(xb + (size_t)(2 * dp + 1) * NPIX + q * 4);
        #pragma unroll
        for (int j = 0; j < 4; ++j) {
            float aj = (j == 0) ? va.x : (j == 1) ? va.y : (j == 2) ? va.z : va.w;
            float bj = (j == 0) ? vb.x : (j == 1) ? vb.y : (j == 2) ? vb.z : vb.w;
            *reinterpret_cast<unsigned int*>(&xT[(q * 4 + j) * XT_ROW + 2 * dp]) = pk(aj, bj);
        }
    }
    // ---- stage Ml: 4096 floats ----
    const float* Mb = M + b * 4096;
    #pragma unroll
    for (int it = 0; it < 4; ++it) {
        int e = it * 256 + tid;
        int c  = e >> 4;
        int qq = e & 15;
        f4 mv = *(const f4*)(Mb + c * 64 + qq * 4);
        *reinterpret_cast<unsigned int*>(&Ml[c * XT_ROW + qq * 4])     = pk(mv.x, mv.y);
        *reinterpret_cast<unsigned int*>(&Ml[c * XT_ROW + qq * 4 + 2]) = pk(mv.z, mv.w);
    }
    __syncthreads();

    const int w    = tid >> 6;
    const int lane = tid & 63;
    const int l15  = lane & 15;
    const int kh   = lane >> 4;       // k-group

    // B fragments: 4 n-blocks x 2 k-steps
    h8 bfrag[4][2];
    #pragma unroll
    for (int nb = 0; nb < 4; ++nb)
        #pragma unroll
        for (int ks = 0; ks < 2; ++ks)
            bfrag[nb][ks] = *reinterpret_cast<const h8*>(
                &xT[(w * 64 + nb * 16 + l15) * XT_ROW + ks * 32 + kh * 8]);

    f4 acc[4][4];   // [cb][nb]
    #pragma unroll
    for (int cb = 0; cb < 4; ++cb)
        #pragma unroll
        for (int nb = 0; nb < 4; ++nb) acc[cb][nb] = (f4){0.f, 0.f, 0.f, 0.f};

    #pragma unroll
    for (int cb = 0; cb < 4; ++cb) {
        #pragma unroll
        for (int ks = 0; ks < 2; ++ks) {
            h8 a = *reinterpret_cast<const h8*>(
                &Ml[(cb * 16 + l15) * XT_ROW + ks * 32 + kh * 8]);
            #pragma unroll
            for (int nb = 0; nb < 4; ++nb)
                acc[cb][nb] = __builtin_amdgcn_mfma_f32_16x16x32_f16(a, bfrag[nb][ks], acc[cb][nb], 0, 0, 0);
        }
    }

    // ---- epilogue: out = acc + x (fp32 residual; x re-read hits L2) ----
    const size_t base = (size_t)b * NC * NPIX + n0 + w * 64;
    #pragma unroll
    for (int cb = 0; cb < 4; ++cb) {
        #pragma unroll
        for (int r = 0; r < 4; ++r) {
            const int row = cb * 16 + kh * 4 + r;
            #pragma unroll
            for (int nb = 0; nb < 4; ++nb) {
                size_t idx = base + (size_t)row * NPIX + nb * 16 + l15;
                out[idx] = acc[cb][nb][r] + x[idx];
            }
        }
    }
}

extern "C" void kernel_launch(void* const* d_in, const int* in_sizes, int n_in,
                              void* d_out, int out_size, void* d_ws, size_t ws_size,
                              hipStream_t stream) {
    const float* x     = (const float*)d_in[0];
    const float* g     = (const float*)d_in[1];
    const float* gamma = (const float*)d_in[2];
    float* out = (float*)d_out;
    float* ws  = (float*)d_ws;

    float* ex = ws;                  // 16*4096 floats
    float* eg = ws + NB * 4096;      // 16*4096 floats
    float* M  = ws + 2 * NB * 4096;  // 16*4096 floats

    // d_out doubles as scratch for the 33.5 MB gram partials; apply_kernel
    // fully overwrites d_out afterwards (stream-ordered), so this is safe.
    float* part = out;

    gram_kernel<<<dim3(NCHUNK, NB), 512, 0, stream>>>(x, g, part);
    reduce_kernel<<<512, 256, 0, stream>>>(part, ex, eg);
    chain_kernel<<<NB, 256, 0, stream>>>(ex, eg, gamma, M);
    apply_kernel<<<dim3(NPIX / AP_NPX, NB), 256, 0, stream>>>(x, M, out);
}

// Round 6
// 268.727 us; speedup vs baseline: 1.7521x; 1.0653x over previous
//
#include <hip/hip_runtime.h>

// ---------------------------------------------------------------------------
// G_CAM_Module: out = gamma * (GA @ x) + x, where GA comes from a chain of
// softmaxed 64x64 Gram matrices of x and g.
//
//   A) gram_kernel  : per-chunk partial Grams via MFMA f16, double-buffered
//                     LDS + reg-prefetch pipeline, ONE barrier per pass
//   B) reduce_kernel: sum 64 chunk-partials -> ex[b], eg[b]
//   C) chain_kernel : softmax chain -> M = gamma*GA   (no identity; tiny fp32)
//   D) apply_kernel : out[b] = M[b] @ x_b + x_b via MFMA f16 (fp32 residual)
// ---------------------------------------------------------------------------

typedef _Float16 h8 __attribute__((ext_vector_type(8)));
typedef float    f4 __attribute__((ext_vector_type(4)));
typedef __fp16   p2 __attribute__((ext_vector_type(2)));   // cvt_pkrtz result
typedef unsigned long long ull;

#define NB 16
#define NC 64
#define NPIX 65536
#define GRAM_CHUNK 1024                 // pixels per gram block
#define PASS_PX 128                     // pixels per LDS pass
#define NPASS (GRAM_CHUNK / PASS_PX)    // 8
#define NCHUNK (NPIX / GRAM_CHUNK)      // 64
#define ROW_H 136                       // gram LDS row stride (halves)
#define LDS_H (64 * ROW_H + 64)         // halves per matrix incl. group pads

#define AP_NPX 256                      // apply: pixels per block
#define XT_ROW 72                       // apply: xT row stride in halves (144B)

__device__ __forceinline__ int rowbase_h(int c) {
    return c * ROW_H + (c >> 3) * 8;
}

__device__ __forceinline__ unsigned int pk(float a, float b) {
    p2 v = __builtin_amdgcn_cvt_pkrtz(a, b);
    return __builtin_bit_cast(unsigned int, v);
}

// ---- Kernel A: partial Gram matrices via MFMA, pipelined ------------------
// grid (64, 16), 512 threads = 8 waves. Waves 0-3: x-gram row-blocks 0-3;
// waves 4-7: g-gram. Pipeline: regs hold pass k+1's global loads while
// buf[k&1] is consumed by MFMA; one __syncthreads per pass.
__global__ __launch_bounds__(512, 2) void gram_kernel(
    const float* __restrict__ x, const float* __restrict__ g,
    float* __restrict__ part)
{
    __shared__ __align__(16) _Float16 lds[2][2 * LDS_H];   // ~70.2 KB

    const int tid = threadIdx.x;
    const int b = blockIdx.y;
    const size_t cbase = (size_t)b * NC * NPIX + (size_t)blockIdx.x * GRAM_CHUNK;

    const int w     = tid >> 6;
    const int lane  = tid & 63;
    const int mtx   = w >> 2;         // 0: x, 1: g
    const int rb    = w & 3;          // C row-block (16 rows)
    const int l15   = lane & 15;
    const int khalf = lane >> 4;      // 0..3 -> which 8-elem k-group
    const int abase_h = rowbase_h(rb * 16 + l15);

    // per-thread staging coordinates (4 tiles of 512 threads cover 64x128)
    const int sc = tid >> 5;          // base channel (it adds 16 per tile)
    const int sq = tid & 31;          // float4 index within 128 px
    const size_t soff = (size_t)sc * NPIX + sq * 4;
    const int lds_off = rowbase_h(sc) + sq * 4;

    f4 acc[4];
    #pragma unroll
    for (int cb = 0; cb < 4; ++cb) acc[cb] = (f4){0.f, 0.f, 0.f, 0.f};

    // ---- prologue: load pass 0 into regs ----
    f4 rx[4], rg[4];
    #pragma unroll
    for (int it = 0; it < 4; ++it) {
        rx[it] = *(const f4*)(x + cbase + soff + (size_t)it * 16 * NPIX);
        rg[it] = *(const f4*)(g + cbase + soff + (size_t)it * 16 * NPIX);
    }

    for (int pass = 0; pass < NPASS; ++pass) {
        _Float16* xs = lds[pass & 1];
        _Float16* gs = lds[pass & 1] + LDS_H;

        // ---- cvt + LDS write of pass k (regs -> buf[k&1]) ----
        #pragma unroll
        for (int it = 0; it < 4; ++it) {
            ull hx = (ull)pk(rx[it].x, rx[it].y) | ((ull)pk(rx[it].z, rx[it].w) << 32);
            ull hg = (ull)pk(rg[it].x, rg[it].y) | ((ull)pk(rg[it].z, rg[it].w) << 32);
            int off = lds_off + it * 16 * ROW_H + it * 2 * 8;  // +16 rows incl pad
            *reinterpret_cast<ull*>(&xs[off]) = hx;
            *reinterpret_cast<ull*>(&gs[off]) = hg;
        }

        // ---- issue global loads for pass k+1 (latency hidden under MFMA) ----
        if (pass + 1 < NPASS) {
            const size_t pbase = cbase + (size_t)(pass + 1) * PASS_PX;
            #pragma unroll
            for (int it = 0; it < 4; ++it) {
                rx[it] = *(const f4*)(x + pbase + soff + (size_t)it * 16 * NPIX);
                rg[it] = *(const f4*)(g + pbase + soff + (size_t)it * 16 * NPIX);
            }
        }

        __syncthreads();   // buf[k&1] ready for all waves

        const _Float16* mybuf = mtx ? gs : xs;
        #pragma unroll
        for (int ks = 0; ks < 4; ++ks) {
            int koff = ks * 32 + khalf * 8;
            h8 a = *reinterpret_cast<const h8*>(&mybuf[abase_h + koff]);
            #pragma unroll
            for (int cb = 0; cb < 4; ++cb) {
                h8 bf = *reinterpret_cast<const h8*>(&mybuf[rowbase_h(cb * 16 + l15) + koff]);
                acc[cb] = __builtin_amdgcn_mfma_f32_16x16x32_f16(a, bf, acc[cb], 0, 0, 0);
            }
        }
        // no trailing barrier: next pass writes the OTHER buffer, and the
        // buffer it does overwrite was last read before the sync above.
    }

    float* po = part + (((size_t)blockIdx.x * NB + b) * 2 + mtx) * 4096;
    #pragma unroll
    for (int cb = 0; cb < 4; ++cb)
        #pragma unroll
        for (int r = 0; r < 4; ++r)
            po[(rb * 16 + khalf * 4 + r) * 64 + cb * 16 + l15] = acc[cb][r];
}

// ---- Kernel B: reduce 64 chunk-partials -> ex, eg -------------------------
__global__ __launch_bounds__(256) void reduce_kernel(
    const float* __restrict__ part, float* __restrict__ ex, float* __restrict__ eg)
{
    const int idx = blockIdx.x * 256 + threadIdx.x;
    const int bm = idx >> 12;          // b*2 + m
    const int cd = idx & 4095;
    float s = 0.f;
    #pragma unroll 8
    for (int ch = 0; ch < NCHUNK; ++ch)
        s += part[(size_t)ch * (NB * 2 * 4096) + (size_t)bm * 4096 + cd];
    float* dst = (bm & 1) ? eg : ex;
    dst[(bm >> 1) * 4096 + cd] = s;
}

// ---- Kernel C: softmax chain -> M = gamma*GA (no identity) ----------------
__global__ __launch_bounds__(256) void chain_kernel(
    const float* __restrict__ ex, const float* __restrict__ eg,
    const float* __restrict__ gammap, float* __restrict__ M)
{
    __shared__ float A1[64][68];
    __shared__ float A2[64][68];
    __shared__ float red[64][4];

    const int b = blockIdx.x;
    const int tid = threadIdx.x;

    if (tid < 64) {
        const int c = tid;
        float r[64];
        #pragma unroll
        for (int d = 0; d < 64; ++d) r[d] = ex[b * 4096 + c * 64 + d];
        float mx = r[0];
        #pragma unroll
        for (int d = 1; d < 64; ++d) mx = fmaxf(mx, r[d]);
        float s = 0.f;
        #pragma unroll
        for (int d = 0; d < 64; ++d) { r[d] = expf(r[d] - mx); s += r[d]; }
        float inv = 1.f / s;
        #pragma unroll
        for (int d = 0; d < 64; ++d) A1[c][d] = r[d] * inv;

        #pragma unroll
        for (int d = 0; d < 64; ++d) r[d] = eg[b * 4096 + c * 64 + d];
        mx = r[0];
        #pragma unroll
        for (int d = 1; d < 64; ++d) mx = fmaxf(mx, r[d]);
        s = 0.f;
        #pragma unroll
        for (int d = 0; d < 64; ++d) { r[d] = expf(r[d] - mx); s += r[d]; }
        inv = 1.f / s;
        #pragma unroll
        for (int d = 0; d < 64; ++d) A2[c][d] = r[d] * inv;
    }
    __syncthreads();

    const int c = tid >> 2, sq = tid & 3;
    float ge[16];
    #pragma unroll
    for (int k = 0; k < 16; ++k) ge[k] = 0.f;
    for (int d = 0; d < 64; ++d) {
        float a = A1[c][d];
        const float* row = &A2[d][sq * 16];
        #pragma unroll
        for (int k = 0; k < 16; ++k) ge[k] = fmaf(a, row[k], ge[k]);
    }

    float mx = ge[0];
    #pragma unroll
    for (int k = 1; k < 16; ++k) mx = fmaxf(mx, ge[k]);
    red[c][sq] = mx;
    __syncthreads();
    float gm = fmaxf(fmaxf(red[c][0], red[c][1]), fmaxf(red[c][2], red[c][3]));
    __syncthreads();

    float gen[16];
    #pragma unroll
    for (int k = 0; k < 16; ++k) gen[k] = gm - ge[k];
    float mx2 = gen[0];
    #pragma unroll
    for (int k = 1; k < 16; ++k) mx2 = fmaxf(mx2, gen[k]);
    red[c][sq] = mx2;
    __syncthreads();
    float m2 = fmaxf(fmaxf(red[c][0], red[c][1]), fmaxf(red[c][2], red[c][3]));
    __syncthreads();

    float p[16];
    float s = 0.f;
    #pragma unroll
    for (int k = 0; k < 16; ++k) { p[k] = expf(gen[k] - m2); s += p[k]; }
    red[c][sq] = s;
    __syncthreads();
    float S = red[c][0] + red[c][1] + red[c][2] + red[c][3];

    float gam = gammap[0];
    float invS = 1.f / S;
    #pragma unroll
    for (int k = 0; k < 16; ++k) {
        int e = sq * 16 + k;
        M[b * 4096 + c * 64 + e] = gam * p[k] * invS;   // NO +I: residual in apply
    }
}

// ---- Kernel D: out[b] = M[b] @ x[b] + x[b] via MFMA ------------------------
__global__ __launch_bounds__(256) void apply_kernel(
    const float* __restrict__ x, const float* __restrict__ M,
    float* __restrict__ out)
{
    __shared__ __align__(16) _Float16 xT[AP_NPX * XT_ROW];   // 36864 B
    __shared__ __align__(16) _Float16 Ml[64 * XT_ROW];       //  9216 B

    const int tid = threadIdx.x;
    const int b = blockIdx.y;
    const int n0 = blockIdx.x * AP_NPX;
    const float* xb = x + (size_t)b * NC * NPIX + n0;

    #pragma unroll
    for (int it = 0; it < 8; ++it) {
        int e = it * 256 + tid;
        int q  = e & 63;          // f4 col (4 pixels)
        int dp = e >> 6;          // d-pair 0..31
        f4 va = *(const f4*)(xb + (size_t)(2 * dp)     * NPIX + q * 4);
        f4 vb = *(const f4*)(xb + (size_t)(2 * dp + 1) * NPIX + q * 4);
        #pragma unroll
        for (int j = 0; j < 4; ++j) {
            float aj = (j == 0) ? va.x : (j == 1) ? va.y : (j == 2) ? va.z : va.w;
            float bj = (j == 0) ? vb.x : (j == 1) ? vb.y : (j == 2) ? vb.z : vb.w;
            *reinterpret_cast<unsigned int*>(&xT[(q * 4 + j) * XT_ROW + 2 * dp]) = pk(aj, bj);
        }
    }
    const float* Mb = M + b * 4096;
    #pragma unroll
    for (int it = 0; it < 4; ++it) {
        int e = it * 256 + tid;
        int c  = e >> 4;
        int qq = e & 15;
        f4 mv = *(const f4*)(Mb + c * 64 + qq * 4);
        *reinterpret_cast<unsigned int*>(&Ml[c * XT_ROW + qq * 4])     = pk(mv.x, mv.y);
        *reinterpret_cast<unsigned int*>(&Ml[c * XT_ROW + qq * 4 + 2]) = pk(mv.z, mv.w);
    }
    __syncthreads();

    const int w    = tid >> 6;
    const int lane = tid & 63;
    const int l15  = lane & 15;
    const int kh   = lane >> 4;

    h8 bfrag[4][2];
    #pragma unroll
    for (int nb = 0; nb < 4; ++nb)
        #pragma unroll
        for (int ks = 0; ks < 2; ++ks)
            bfrag[nb][ks] = *reinterpret_cast<const h8*>(
                &xT[(w * 64 + nb * 16 + l15) * XT_ROW + ks * 32 + kh * 8]);

    f4 acc[4][4];   // [cb][nb]
    #pragma unroll
    for (int cb = 0; cb < 4; ++cb)
        #pragma unroll
        for (int nb = 0; nb < 4; ++nb) acc[cb][nb] = (f4){0.f, 0.f, 0.f, 0.f};

    #pragma unroll
    for (int cb = 0; cb < 4; ++cb) {
        #pragma unroll
        for (int ks = 0; ks < 2; ++ks) {
            h8 a = *reinterpret_cast<const h8*>(
                &Ml[(cb * 16 + l15) * XT_ROW + ks * 32 + kh * 8]);
            #pragma unroll
            for (int nb = 0; nb < 4; ++nb)
                acc[cb][nb] = __builtin_amdgcn_mfma_f32_16x16x32_f16(a, bfrag[nb][ks], acc[cb][nb], 0, 0, 0);
        }
    }

    const size_t base = (size_t)b * NC * NPIX + n0 + w * 64;
    #pragma unroll
    for (int cb = 0; cb < 4; ++cb) {
        #pragma unroll
        for (int r = 0; r < 4; ++r) {
            const int row = cb * 16 + kh * 4 + r;
            #pragma unroll
            for (int nb = 0; nb < 4; ++nb) {
                size_t idx = base + (size_t)row * NPIX + nb * 16 + l15;
                out[idx] = acc[cb][nb][r] + x[idx];
            }
        }
    }
}

extern "C" void kernel_launch(void* const* d_in, const int* in_sizes, int n_in,
                              void* d_out, int out_size, void* d_ws, size_t ws_size,
                              hipStream_t stream) {
    const float* x     = (const float*)d_in[0];
    const float* g     = (const float*)d_in[1];
    const float* gamma = (const float*)d_in[2];
    float* out = (float*)d_out;
    float* ws  = (float*)d_ws;

    float* ex = ws;                  // 16*4096 floats
    float* eg = ws + NB * 4096;      // 16*4096 floats
    float* M  = ws + 2 * NB * 4096;  // 16*4096 floats

    // d_out doubles as scratch for the 33.5 MB gram partials; apply_kernel
    // fully overwrites d_out afterwards (stream-ordered), so this is safe.
    float* part = out;

    gram_kernel<<<dim3(NCHUNK, NB), 512, 0, stream>>>(x, g, part);
    reduce_kernel<<<512, 256, 0, stream>>>(part, ex, eg);
    chain_kernel<<<NB, 256, 0, stream>>>(ex, eg, gamma, M);
    apply_kernel<<<dim3(NPIX / AP_NPX, NB), 256, 0, stream>>>(x, M, out);
}